// Round 5
// baseline (458.504 us; speedup 1.0000x reference)
//
#include <hip/hip_runtime.h>
#include <hip/hip_bf16.h>

// B=2, C=8, L=1024, H=512
// out[((b*1024+l)*1024+m)*8 + c] = a[b,c,l] + bb[b,c,m] + sum_h start*v4*end
//
// Single fused kernel. WG tile = 64(l) x 64(m) x all 8 c-planes, K=512 in 16
// steps of BK=32. Wave w owns planes {2w, 2w+1} END-TO-END: it stages them
// into its own disjoint LDS region, computes their a/bb sums, reads its own
// fragments, and accumulates their 64x64 output. => NO __syncthreads in the
// K-loop (DS ops within a wave complete in order). Each of the 8 resident
// waves/CU pipelines independently (R4 was barrier-convoyed at 2 WG/CU).
// Epilogue (unchanged from R4): fold sums, LDS-transpose, full-line stores.

typedef short bf16x8 __attribute__((ext_vector_type(8)));
typedef float f32x4 __attribute__((ext_vector_type(4)));

__device__ __forceinline__ unsigned pk2(float x, float y) {
    union { __hip_bfloat162 h; unsigned u; } cv;
    cv.h = __float22bfloat162_rn(make_float2(x, y));
    return cv.u;
}

__device__ __forceinline__ float dot8(float4 a0, float4 a1, float4 w0, float4 w1) {
    return a0.x*w0.x + a0.y*w0.y + a0.z*w0.z + a0.w*w0.w
         + a1.x*w1.x + a1.y*w1.y + a1.z*w1.z + a1.w*w1.w;
}

// K-loop LDS layout with row-pair XOR swizzle (no padding; 2-way = free).
__device__ __forceinline__ int lds_off(int plane, int row, int j) {
    const int rp = row >> 1;
    const int pc = (j + ((row & 1) << 2)) ^ (rp & 7);
    return plane * 2048 + rp * 64 + pc * 8;
}

__global__ __launch_bounds__(256, 2) void fused_k(const float* __restrict__ sh,
                                                  const float* __restrict__ eh,
                                                  const float* __restrict__ v,
                                                  float* __restrict__ out) {
    __shared__ __align__(16) unsigned char smem[65536];
    unsigned short* As = (unsigned short*)smem;      // [plane 0..7][2048] = 32 KB
    unsigned short* Bs = As + 8 * 2048;              // 32 KB

    const int t   = threadIdx.x;
    const int bid = blockIdx.x;
    // XCD swizzle: all 16 mt-blocks of a (b,lt) strip land on one XCD.
    const int xcd  = bid & 7, slot = bid >> 3;
    const int b    = xcd >> 2;
    const int lt   = (xcd & 3) * 4 + (slot >> 4);
    const int mt   = slot & 15;

    const int lane = t & 63, wave = t >> 6;
    const int ln15 = lane & 15, quad = lane >> 4;

    const int rsub = lane >> 2;   // 0..15 staging row-sub
    const int kc   = lane & 3;    // 8-float k-chunk within BK=32

    // this wave's two planes (within batch b): 2*wave, 2*wave+1
    const float* baseA = sh + ((size_t)b * 8 + 2 * wave) * 524288 + ((size_t)lt * 64 + rsub) * 512;
    const float* baseB = eh + ((size_t)b * 8 + 2 * wave) * 524288 + ((size_t)mt * 64 + rsub) * 512;

    f32x4 acc[2][4][4] = {};
    float sa[2][4] = {}, sb[2][4] = {};

    // group g of a K-step: 0 = A/plane0, 1 = B/plane0, 2 = A/plane1, 3 = B/plane1
    float4 buf[2][8];
    auto load_group = [&](int ks, int g, float4* dst) {
        const int cp = g >> 1;
        const float* bse = (g & 1) ? baseB : baseA;
        const float* p0 = bse + (size_t)cp * 524288 + ks * 32 + kc * 8;
        #pragma unroll
        for (int p = 0; p < 4; ++p) {
            dst[2 * p]     = *(const float4*)(p0 + p * 8192);
            dst[2 * p + 1] = *(const float4*)(p0 + p * 8192 + 4);
        }
    };

    load_group(0, 0, buf[0]);

    #pragma unroll 1
    for (int ks = 0; ks < 16; ++ks) {
        const int k0 = ks * 32 + kc * 8;
        float4 w1a = *(const float4*)(v + k0);          float4 w1b = *(const float4*)(v + k0 + 4);
        float4 w2a = *(const float4*)(v + 512 + k0);    float4 w2b = *(const float4*)(v + 512 + k0 + 4);
        float4 w3a = *(const float4*)(v + 1024 + k0);   float4 w3b = *(const float4*)(v + 1024 + k0 + 4);
        float4 w4a = *(const float4*)(v + 1536 + k0);   float4 w4b = *(const float4*)(v + 1536 + k0 + 4);
        const float4 wAa = make_float4(w1a.x + w3a.x, w1a.y + w3a.y, w1a.z + w3a.z, w1a.w + w3a.w);
        const float4 wAb = make_float4(w1b.x + w3b.x, w1b.y + w3b.y, w1b.z + w3b.z, w1b.w + w3b.w);
        const float4 wBa = make_float4(w2a.x - w3a.x, w2a.y - w3a.y, w2a.z - w3a.z, w2a.w - w3a.w);
        const float4 wBb = make_float4(w2b.x - w3b.x, w2b.y - w3b.y, w2b.z - w3b.z, w2b.w - w3b.w);

        #pragma unroll
        for (int g = 0; g < 4; ++g) {
            // prefetch next group (crosses into next K-step at g==3)
            if (!(ks == 15 && g == 3))
                load_group(g == 3 ? ks + 1 : ks, (g + 1) & 3, buf[(g + 1) & 1]);

            float4* cur = buf[g & 1];
            const int cp = g >> 1;
            if ((g & 1) == 0) {          // A-type: sums + v4-scale + pack
                #pragma unroll
                for (int p = 0; p < 4; ++p) {
                    float4 a0 = cur[2 * p], a1 = cur[2 * p + 1];
                    sa[cp][p] += dot8(a0, a1, wAa, wAb);
                    a0.x *= w4a.x; a0.y *= w4a.y; a0.z *= w4a.z; a0.w *= w4a.w;
                    a1.x *= w4b.x; a1.y *= w4b.y; a1.z *= w4b.z; a1.w *= w4b.w;
                    uint4 pk;
                    pk.x = pk2(a0.x, a0.y); pk.y = pk2(a0.z, a0.w);
                    pk.z = pk2(a1.x, a1.y); pk.w = pk2(a1.z, a1.w);
                    *(uint4*)&As[lds_off(2 * wave + cp, rsub + 16 * p, kc)] = pk;
                }
            } else {                     // B-type: sums + pack
                #pragma unroll
                for (int p = 0; p < 4; ++p) {
                    float4 b0 = cur[2 * p], b1 = cur[2 * p + 1];
                    sb[cp][p] += dot8(b0, b1, wBa, wBb);
                    uint4 pk;
                    pk.x = pk2(b0.x, b0.y); pk.y = pk2(b0.z, b0.w);
                    pk.z = pk2(b1.x, b1.y); pk.w = pk2(b1.z, b1.w);
                    *(uint4*)&Bs[lds_off(2 * wave + cp, rsub + 16 * p, kc)] = pk;
                }
            }
        }

        // fragments from this wave's own LDS region (in-order DS => no barrier)
        bf16x8 aF[2][4], bF[2][4];
        #pragma unroll
        for (int c2 = 0; c2 < 2; ++c2) {
            const int c = 2 * wave + c2;
            #pragma unroll
            for (int i = 0; i < 4; ++i) {
                aF[c2][i] = *(const bf16x8*)&As[lds_off(c, i * 16 + ln15, quad)];
                bF[c2][i] = *(const bf16x8*)&Bs[lds_off(c, i * 16 + ln15, quad)];
            }
        }
        #pragma unroll
        for (int c2 = 0; c2 < 2; ++c2)
            #pragma unroll
            for (int i = 0; i < 4; ++i)
                #pragma unroll
                for (int j = 0; j < 4; ++j)
                    acc[c2][i][j] = __builtin_amdgcn_mfma_f32_16x16x32_bf16(
                        aF[c2][i], bF[c2][j], acc[c2][i][j], 0, 0, 0);
    }

    // ---- per-wave sums: reduce over the 4 k-chunk lanes, stash in own LDS ----
    float* sums_w = (float*)(smem + wave * 8192);   // [a: cp*64+row][bb at +128]
    #pragma unroll
    for (int cp = 0; cp < 2; ++cp)
        #pragma unroll
        for (int p = 0; p < 4; ++p) {
            float x = sa[cp][p], y = sb[cp][p];
            x += __shfl_xor(x, 1, 64); x += __shfl_xor(x, 2, 64);
            y += __shfl_xor(y, 1, 64); y += __shfl_xor(y, 2, 64);
            if (kc == 0) {
                sums_w[cp * 64 + rsub + 16 * p]       = x;
                sums_w[128 + cp * 64 + rsub + 16 * p] = y;
            }
        }

    // ---- fold a + bb into acc (all data is this wave's own) ----
    {
        float avv[2][4][4], bvv[2][4];
        #pragma unroll
        for (int c2 = 0; c2 < 2; ++c2) {
            #pragma unroll
            for (int i = 0; i < 4; ++i)
                #pragma unroll
                for (int r = 0; r < 4; ++r)
                    avv[c2][i][r] = sums_w[c2 * 64 + i * 16 + quad * 4 + r];
            #pragma unroll
            for (int j = 0; j < 4; ++j)
                bvv[c2][j] = sums_w[128 + c2 * 64 + j * 16 + ln15];
        }
        #pragma unroll
        for (int c2 = 0; c2 < 2; ++c2)
            #pragma unroll
            for (int i = 0; i < 4; ++i)
                #pragma unroll
                for (int j = 0; j < 4; ++j)
                    #pragma unroll
                    for (int r = 0; r < 4; ++r)
                        acc[c2][i][j][r] += avv[c2][i][r] + bvv[c2][j];
    }
    __syncthreads();   // everyone done with K-loop smem; reuse for transpose

    // ---- epilogue: LDS transpose per 32-row half, fully coalesced stores ----
    float2* T = (float2*)smem;   // [wave][i2*16 + j*4 + r][lane] float2 = 64 KB
    const int chalf = t & 1;
    #pragma unroll
    for (int half = 0; half < 2; ++half) {
        #pragma unroll
        for (int i2 = 0; i2 < 2; ++i2)
            #pragma unroll
            for (int j = 0; j < 4; ++j)
                #pragma unroll
                for (int r = 0; r < 4; ++r)
                    T[wave * 2048 + (i2 * 16 + j * 4 + r) * 64 + lane] =
                        make_float2(acc[0][half * 2 + i2][j][r],
                                    acc[1][half * 2 + i2][j][r]);
        __syncthreads();
        #pragma unroll
        for (int iter = 0; iter < 16; ++iter) {
            const int slotp = iter * 128 + (t >> 1);      // 0..2047
            const int llp = slotp >> 6, mm = slotp & 63;  // half-local l, m
            const int i2 = llp >> 4, q2 = (llp >> 2) & 3, r = llp & 3;
            const int j = mm >> 4, ln = mm & 15;
            const int lidx = (i2 * 16 + j * 4 + r) * 64 + q2 * 16 + ln;
            const float2 lo = T[(chalf * 2 + 0) * 2048 + lidx];
            const float2 hi = T[(chalf * 2 + 1) * 2048 + lidx];
            const int l = lt * 64 + half * 32 + llp;
            const int m = mt * 64 + mm;
            *(float4*)&out[((size_t)(b * 1024 + l) * 1024 + m) * 8 + chalf * 4] =
                make_float4(lo.x, lo.y, hi.x, hi.y);
        }
        if (half == 0) __syncthreads();
    }
}

extern "C" void kernel_launch(void* const* d_in, const int* in_sizes, int n_in,
                              void* d_out, int out_size, void* d_ws, size_t ws_size,
                              hipStream_t stream) {
    const float* sh = (const float*)d_in[0];
    const float* eh = (const float*)d_in[1];
    const float* v  = (const float*)d_in[2];
    float* out = (float*)d_out;
    (void)d_ws; (void)ws_size; (void)in_sizes; (void)n_in; (void)out_size;

    fused_k<<<512, 256, 0, stream>>>(sh, eh, v, out);
}